// Round 2
// baseline (380.592 us; speedup 1.0000x reference)
//
#include <hip/hip_runtime.h>

// Problem: NUM_EXPERTS=64, N=67108864 tokens.
// Output 0: m_out[N]  (int32)  -- expert id per slot, or m_in passthrough past `total`
// Output 1: starts[64] (int32) -- exclusive cumsum of counts
//
// Kernel 1: 1 wave, shfl prefix-sum of 64 counts -> starts (to d_out+N) and
//           starts+total (to d_ws, consumed by kernel 2; stream order gives
//           device-scope visibility across the kernel boundary).
// Kernel 2: write-BW-bound fill. 64-entry starts table in LDS, 6-step
//           branchless upper_bound-1 per element; int4 stores.

#define N_EXPERTS 64
#define BLOCK 256
#define V4_PER_THREAD 4
#define ELEMS_PER_BLOCK (BLOCK * 4 * V4_PER_THREAD)  // 16384

__global__ void moe_scan_kernel(const int* __restrict__ counts,
                                int* __restrict__ starts_out,
                                int* __restrict__ ws) {
    int lane = threadIdx.x;  // 64 threads, one wave
    int c = counts[lane];
    int x = c;
#pragma unroll
    for (int off = 1; off < 64; off <<= 1) {
        int y = __shfl_up(x, off, 64);
        if (lane >= off) x += y;
    }
    int start = x - c;               // exclusive prefix
    starts_out[lane] = start;        // output 1
    ws[lane] = start;                // table for fill kernel
    if (lane == 63) ws[64] = x;      // total = inclusive sum at lane 63
}

// last j in [0,63] with s[j] <= i  (s[0]==0 <= i always)
__device__ __forceinline__ int upper_bound_m1(const int* __restrict__ s, int i) {
    int e = 0;
#pragma unroll
    for (int step = 32; step >= 1; step >>= 1) {
        if (s[e + step] <= i) e += step;   // e+step <= 63 by construction
    }
    return e;
}

__global__ __launch_bounds__(BLOCK) void moe_fill_kernel(
    const int* __restrict__ ws,      // starts[64], total at [64]
    const int* __restrict__ m_in,
    int* __restrict__ m_out,
    int n) {
    __shared__ int s_starts[N_EXPERTS];
    __shared__ int s_total_sh;
    int tid = threadIdx.x;
    if (tid < N_EXPERTS) s_starts[tid] = ws[tid];
    if (tid == 0) s_total_sh = ws[N_EXPERTS];
    __syncthreads();

    int total = s_total_sh;
    if (total > n) total = n;
    if (total < 0) total = 0;

    int blockBase = blockIdx.x * ELEMS_PER_BLOCK;
#pragma unroll
    for (int v = 0; v < V4_PER_THREAD; ++v) {
        int i0 = blockBase + (v * BLOCK + tid) * 4;
        if (i0 >= n) break;
        int4 outv;
        if (i0 + 3 < total) {
            // pure expert-id region
            int e0 = upper_bound_m1(s_starts, i0);
            int e3 = upper_bound_m1(s_starts, i0 + 3);
            if (e0 == e3) {
                outv.x = e0; outv.y = e0; outv.z = e0; outv.w = e0;
            } else {
                outv.x = e0;
                outv.y = upper_bound_m1(s_starts, i0 + 1);
                outv.z = upper_bound_m1(s_starts, i0 + 2);
                outv.w = e3;
            }
        } else if (i0 >= total) {
            // pure passthrough region
            outv = *reinterpret_cast<const int4*>(m_in + i0);
        } else {
            // straddles `total`
            int vals[4];
#pragma unroll
            for (int j = 0; j < 4; ++j) {
                int i = i0 + j;
                vals[j] = (i < total) ? upper_bound_m1(s_starts, i) : m_in[i];
            }
            outv.x = vals[0]; outv.y = vals[1]; outv.z = vals[2]; outv.w = vals[3];
        }
        *reinterpret_cast<int4*>(m_out + i0) = outv;
    }
}

extern "C" void kernel_launch(void* const* d_in, const int* in_sizes, int n_in,
                              void* d_out, int out_size, void* d_ws, size_t ws_size,
                              hipStream_t stream) {
    const int* counts = (const int*)d_in[0];
    // d_in[1] = expert_start_loc (unused; reference recomputes starts)
    const int* m_in = (const int*)d_in[2];
    int n = in_sizes[2];                 // 67108864
    int* out = (int*)d_out;              // m_out[n] then starts[64]
    int* starts_out = out + n;
    int* ws = (int*)d_ws;                // 65 ints

    moe_scan_kernel<<<1, 64, 0, stream>>>(counts, starts_out, ws);

    int blocks = (n + ELEMS_PER_BLOCK - 1) / ELEMS_PER_BLOCK;  // 4096
    moe_fill_kernel<<<blocks, BLOCK, 0, stream>>>(ws, m_in, out, n);
}

// Round 3
// 378.349 us; speedup vs baseline: 1.0059x; 1.0059x over previous
//
#include <hip/hip_runtime.h>

// MoE dispatch-index fill. NUM_EXPERTS=64, N=67108864.
// Output 0: m_out[N] (int32) -- expert id per slot for i < total, else m_in[i]
// Output 1: starts[64] (int32) -- exclusive cumsum of counts
//
// Single fused kernel: every block redundantly computes the 64-wide exclusive
// scan (256 B read, L2-cached; one wave, 6 shfl_up steps) -> no scan kernel,
// no ws dependency, one launch. Block 0 also writes starts to d_out+N.
//
// Fill fast path: a block spans 16384 slots but expert segments average ~1M,
// so ~99.6% of blocks lie inside ONE expert's segment -> constant int4 store
// stream (same shape as rocclr fillBuffer, which hits 6.4 TB/s). Binary
// search runs only twice per block on this path (block start / block end).

#define N_EXPERTS 64
#define BLOCK 256
#define V4_PER_THREAD 4
#define ELEMS_PER_BLOCK (BLOCK * 4 * V4_PER_THREAD)  // 16384

// last j in [0,63] with s[j] <= i  (s[0]==0 <= i always; never reads s[64])
__device__ __forceinline__ int upper_bound_m1(const int* __restrict__ s, int i) {
    int e = 0;
#pragma unroll
    for (int step = 32; step >= 1; step >>= 1) {
        if (s[e + step] <= i) e += step;
    }
    return e;
}

__global__ __launch_bounds__(BLOCK) void moe_fused_kernel(
    const int* __restrict__ counts,
    const int* __restrict__ m_in,
    int* __restrict__ m_out,
    int* __restrict__ starts_out,
    int n) {
    __shared__ int s_starts[N_EXPERTS + 1];  // [64] = total
    int tid = threadIdx.x;

    if (tid < 64) {  // wave 0 exactly: full-wave shfl is safe
        int c = counts[tid];
        int x = c;
#pragma unroll
        for (int off = 1; off < 64; off <<= 1) {
            int y = __shfl_up(x, off, 64);
            if (tid >= off) x += y;
        }
        s_starts[tid] = x - c;
        if (tid == 63) s_starts[64] = x;  // total
        if (blockIdx.x == 0) starts_out[tid] = x - c;  // output 1
    }
    __syncthreads();

    int total = s_starts[64];
    if (total > n) total = n;
    if (total < 0) total = 0;

    int blockBase = blockIdx.x * ELEMS_PER_BLOCK;
    if (blockBase >= n) return;
    int blockEnd = blockBase + ELEMS_PER_BLOCK;
    bool fullBlock = (blockEnd <= n);
    if (!fullBlock) blockEnd = n;

    if (fullBlock && blockEnd <= total) {
        int eA = upper_bound_m1(s_starts, blockBase);
        int eB = upper_bound_m1(s_starts, blockEnd - 1);
        if (eA == eB) {
            // ---- fast path: whole block is one expert id; pure store stream
            int4 val; val.x = eA; val.y = eA; val.z = eA; val.w = eA;
#pragma unroll
            for (int v = 0; v < V4_PER_THREAD; ++v) {
                int i0 = blockBase + (v * BLOCK + tid) * 4;
                *reinterpret_cast<int4*>(m_out + i0) = val;
            }
            return;
        }
    } else if (fullBlock && blockBase >= total) {
        // ---- pure passthrough: vector copy m_in -> m_out
#pragma unroll
        for (int v = 0; v < V4_PER_THREAD; ++v) {
            int i0 = blockBase + (v * BLOCK + tid) * 4;
            *reinterpret_cast<int4*>(m_out + i0) =
                *reinterpret_cast<const int4*>(m_in + i0);
        }
        return;
    }

    // ---- general path: boundary blocks (expert boundary, `total`, or n tail)
#pragma unroll
    for (int v = 0; v < V4_PER_THREAD; ++v) {
        int i0 = blockBase + (v * BLOCK + tid) * 4;
        if (i0 >= n) break;
        int4 outv;
        if (i0 + 3 < total) {
            int e0 = upper_bound_m1(s_starts, i0);
            int e3 = upper_bound_m1(s_starts, i0 + 3);
            if (e0 == e3) {
                outv.x = e0; outv.y = e0; outv.z = e0; outv.w = e0;
            } else {
                outv.x = e0;
                outv.y = upper_bound_m1(s_starts, i0 + 1);
                outv.z = upper_bound_m1(s_starts, i0 + 2);
                outv.w = e3;
            }
        } else if (i0 >= total) {
            outv = *reinterpret_cast<const int4*>(m_in + i0);
        } else {
            int vals[4];
#pragma unroll
            for (int j = 0; j < 4; ++j) {
                int i = i0 + j;
                vals[j] = (i < total) ? upper_bound_m1(s_starts, i) : m_in[i];
            }
            outv.x = vals[0]; outv.y = vals[1]; outv.z = vals[2]; outv.w = vals[3];
        }
        *reinterpret_cast<int4*>(m_out + i0) = outv;
    }
}

extern "C" void kernel_launch(void* const* d_in, const int* in_sizes, int n_in,
                              void* d_out, int out_size, void* d_ws, size_t ws_size,
                              hipStream_t stream) {
    const int* counts = (const int*)d_in[0];
    // d_in[1] = expert_start_loc (unused; reference recomputes starts)
    const int* m_in = (const int*)d_in[2];
    int n = in_sizes[2];                 // 67108864
    int* out = (int*)d_out;              // m_out[n] then starts[64]
    int* starts_out = out + n;

    int blocks = (n + ELEMS_PER_BLOCK - 1) / ELEMS_PER_BLOCK;  // 4096
    moe_fused_kernel<<<blocks, BLOCK, 0, stream>>>(counts, m_in, out, starts_out, n);
}